// Round 1
// baseline (1380.864 us; speedup 1.0000x reference)
//
#include <hip/hip_runtime.h>
#include <hip/hip_bf16.h>
#include <math.h>

#define NN 20000
#define EE 320000
#define NFD 74
#define EFD 12

__device__ __forceinline__ float leakyf(float x) { return x > 0.f ? x : 0.01f * x; }

// ---------------- generic tiled fp32 GEMM: C = act(A@B + bias) ----------------
// A: [nrows, >=a_off+K] row-major stride lda (uses cols a_off..a_off+K)
// B: [K, >=M] row-major stride ldb
// C: [nrows, ldc], writes cols c_off..c_off+M
// ACT: 0 none, 1 leaky, 2 elu-with-cnt-guard
template <int ACT>
__global__ __launch_bounds__(256) void gemm_k(
    const float* __restrict__ A, int lda, int a_off,
    const float* __restrict__ B, int ldb,
    const float* __restrict__ bias,
    float* __restrict__ C, int ldc, int c_off,
    int nrows, int K, int M,
    const int* __restrict__ cnt)
{
    const int tiles_m = (M + 63) >> 6;
    const int tn = blockIdx.x / tiles_m;
    const int tm = blockIdx.x % tiles_m;
    const int n0 = tn << 6, m0 = tm << 6;
    __shared__ float As[32][68];
    __shared__ float Bs[32][68];
    const int tid = threadIdx.x;
    const int ai = tid >> 2, aj = (tid & 3) * 8;
    const int bj = tid >> 3, bc = (tid & 7) * 8;
    const int nn4 = (tid & 15) << 2, cc4 = (tid >> 4) << 2;
    float acc[4][4];
#pragma unroll
    for (int i = 0; i < 4; i++)
#pragma unroll
        for (int j = 0; j < 4; j++) acc[i][j] = 0.f;

    for (int k0 = 0; k0 < K; k0 += 32) {
        {
            const int grow = n0 + ai;
            const bool rok = grow < nrows;
            const float* Ap = A + (size_t)grow * lda + a_off + k0 + aj;
#pragma unroll
            for (int r = 0; r < 8; r++) {
                int gj = k0 + aj + r;
                As[aj + r][ai] = (rok && gj < K) ? Ap[r] : 0.f;
            }
        }
        {
            const int gj = k0 + bj;
            const bool jok = gj < K;
            const float* Bp = B + (size_t)gj * ldb + m0 + bc;
#pragma unroll
            for (int r = 0; r < 8; r++) {
                int gc = m0 + bc + r;
                Bs[bj][bc + r] = (jok && gc < M) ? Bp[r] : 0.f;
            }
        }
        __syncthreads();
#pragma unroll
        for (int j = 0; j < 32; j++) {
            float4 av = *(const float4*)&As[j][nn4];
            float4 bv = *(const float4*)&Bs[j][cc4];
            acc[0][0] += av.x * bv.x; acc[0][1] += av.x * bv.y; acc[0][2] += av.x * bv.z; acc[0][3] += av.x * bv.w;
            acc[1][0] += av.y * bv.x; acc[1][1] += av.y * bv.y; acc[1][2] += av.y * bv.z; acc[1][3] += av.y * bv.w;
            acc[2][0] += av.z * bv.x; acc[2][1] += av.z * bv.y; acc[2][2] += av.z * bv.z; acc[2][3] += av.z * bv.w;
            acc[3][0] += av.w * bv.x; acc[3][1] += av.w * bv.y; acc[3][2] += av.w * bv.z; acc[3][3] += av.w * bv.w;
        }
        __syncthreads();
    }
#pragma unroll
    for (int i = 0; i < 4; i++) {
        const int gr = n0 + nn4 + i;
        if (gr >= nrows) continue;
        const bool pos = (ACT != 2) || (cnt[gr] > 0);
#pragma unroll
        for (int j = 0; j < 4; j++) {
            const int gc = m0 + cc4 + j;
            if (gc >= M) continue;
            float v = acc[i][j] + bias[gc];
            if (ACT == 1) v = leakyf(v);
            else if (ACT == 2) v = pos ? (v > 0.f ? v : (__expf(v) - 1.f)) : 0.f;
            C[(size_t)gr * ldc + c_off + gc] = v;
        }
    }
}

// ---------------- qa_k[n] = hv_k[n] . w2a_k  (wave per node) ----------------
__global__ __launch_bounds__(256) void k_qa(
    const float* __restrict__ HV,
    const float* __restrict__ w0, const float* __restrict__ w1, const float* __restrict__ w2,
    float* __restrict__ QA)
{
    int n = (blockIdx.x << 2) + (threadIdx.x >> 6);
    if (n >= NN) return;
    int lane = threadIdx.x & 63;
    int c0 = lane * 2;
    const float* hr = HV + (size_t)n * 384;
    const float* ws[3] = {w0, w1, w2};
#pragma unroll
    for (int k = 0; k < 3; k++) {
        float2 h = *(const float2*)(hr + k * 128 + c0);
        float2 wv = *(const float2*)(ws[k] + c0);
        float part = h.x * wv.x + h.y * wv.y;
#pragma unroll
        for (int m = 1; m < 64; m <<= 1) part += __shfl_xor(part, m, 64);
        if (lane == 0) QA[k * NN + n] = part;
    }
}

// ---------------- CSR build ----------------
__global__ void k_count(const int* __restrict__ dst, int* __restrict__ cnt)
{
    int e = blockIdx.x * 256 + threadIdx.x;
    if (e < EE) atomicAdd(&cnt[dst[e]], 1);
}

__global__ __launch_bounds__(1024) void k_scan(
    const int* __restrict__ cnt, int* __restrict__ off, int* __restrict__ cur, int n)
{
    __shared__ int warp_sums[16];
    __shared__ int s_run;
    int tid = threadIdx.x;
    int lane = tid & 63, wid = tid >> 6;
    if (tid == 0) s_run = 0;
    __syncthreads();
    for (int base = 0; base < n; base += 1024) {
        int i = base + tid;
        int v = (i < n) ? cnt[i] : 0;
        int x = v;
#pragma unroll
        for (int d = 1; d < 64; d <<= 1) { int y = __shfl_up(x, d, 64); if (lane >= d) x += y; }
        if (lane == 63) warp_sums[wid] = x;
        __syncthreads();
        if (wid == 0) {
            int wv = (lane < 16) ? warp_sums[lane] : 0;
#pragma unroll
            for (int d = 1; d < 16; d <<= 1) { int y = __shfl_up(wv, d, 64); if (lane >= d) wv += y; }
            if (lane < 16) warp_sums[lane] = wv;
        }
        __syncthreads();
        int wave_off = (wid > 0) ? warp_sums[wid - 1] : 0;
        int incl = x + wave_off;
        int run = s_run;
        int excl = run + incl - v;
        if (i < n) { off[i] = excl; cur[i] = excl; }
        __syncthreads();
        if (tid == 1023) s_run = run + incl;
        __syncthreads();
    }
    if (tid == 0) off[n] = s_run;
}

__global__ void k_fill(const int* __restrict__ dst, int* __restrict__ cur, int* __restrict__ csr)
{
    int e = blockIdx.x * 256 + threadIdx.x;
    if (e < EE) { int p = atomicAdd(&cur[dst[e]], 1); csr[p] = e; }
}

// ---------------- edge logits: lg[k][e] (wave per edge) ----------------
__global__ __launch_bounds__(256) void k_logits(
    const float* __restrict__ PN, const float* __restrict__ QA,
    const float* __restrict__ ef,
    const float* __restrict__ pw0, const float* __restrict__ pw1, const float* __restrict__ pw2,
    const float* __restrict__ v0, const float* __restrict__ v1, const float* __restrict__ v2,
    const float* __restrict__ b0, const float* __restrict__ b1, const float* __restrict__ b2,
    const int* __restrict__ src, const int* __restrict__ dst,
    float* __restrict__ LG)
{
    int e = (blockIdx.x << 2) + (threadIdx.x >> 6);
    if (e >= EE) return;
    int lane = threadIdx.x & 63;
    int c0 = lane * 2;
    int sn = src[e], dn = dst[e];
    const float4* ef4 = (const float4*)(ef + (size_t)e * 12);
    float4 ea = ef4[0], eb = ef4[1], ec = ef4[2];
    float efv[12] = {ea.x, ea.y, ea.z, ea.w, eb.x, eb.y, eb.z, eb.w, ec.x, ec.y, ec.z, ec.w};
    const float* pnrow = PN + (size_t)sn * 384;
    const float* pws[3] = {pw0, pw1, pw2};
    const float* vs[3] = {v0, v1, v2};
    const float* bs[3] = {b0, b1, b2};
#pragma unroll
    for (int k = 0; k < 3; k++) {
        float2 p = *(const float2*)(pnrow + k * 128 + c0);
        float x0 = p.x, x1 = p.y;
        const float* w = pws[k] + NFD * 128 + c0;
#pragma unroll
        for (int j = 0; j < 12; j++) {
            float2 wv = *(const float2*)(w + j * 128);
            x0 += efv[j] * wv.x; x1 += efv[j] * wv.y;
        }
        x0 = leakyf(x0); x1 = leakyf(x1);
        float2 wb = *(const float2*)(vs[k] + 128 + c0);
        float part = x0 * wb.x + x1 * wb.y;
#pragma unroll
        for (int m = 1; m < 64; m <<= 1) part += __shfl_xor(part, m, 64);
        if (lane == 0) {
            float lg = leakyf(QA[k * NN + dn] + part + bs[k][0]);
            LG[(size_t)k * EE + e] = lg;
        }
    }
}

// ---------------- per-node softmax-weighted aggregation (wave per node) ----------------
__global__ __launch_bounds__(256) void k_aggr(
    const float* __restrict__ PN, const float* __restrict__ LG,
    const float* __restrict__ ef,
    const float* __restrict__ pw0, const float* __restrict__ pw1, const float* __restrict__ pw2,
    const int* __restrict__ src,
    const int* __restrict__ offp, const int* __restrict__ csr,
    float* __restrict__ A)
{
    int n = (blockIdx.x << 2) + (threadIdx.x >> 6);
    if (n >= NN) return;
    int lane = threadIdx.x & 63;
    int c0 = lane * 2;
    int o0 = offp[n], deg = offp[n + 1] - o0;
    float* arow = A + (size_t)n * 384;
    if (deg == 0) {
#pragma unroll
        for (int k = 0; k < 3; k++) *(float2*)(arow + k * 128 + c0) = make_float2(0.f, 0.f);
        return;
    }
    float m0 = -1e30f, m1 = -1e30f, m2 = -1e30f;
    for (int b = 0; b < deg; b += 64) {
        int i = b + lane;
        if (i < deg) {
            int eid = csr[o0 + i];
            m0 = fmaxf(m0, LG[eid]);
            m1 = fmaxf(m1, LG[EE + eid]);
            m2 = fmaxf(m2, LG[2 * EE + eid]);
        }
    }
#pragma unroll
    for (int m = 1; m < 64; m <<= 1) {
        m0 = fmaxf(m0, __shfl_xor(m0, m, 64));
        m1 = fmaxf(m1, __shfl_xor(m1, m, 64));
        m2 = fmaxf(m2, __shfl_xor(m2, m, 64));
    }
    float s0 = 0.f, s1 = 0.f, s2 = 0.f;
    float acc[3][2] = {{0.f, 0.f}, {0.f, 0.f}, {0.f, 0.f}};
    const float* pws[3] = {pw0, pw1, pw2};
    for (int i = 0; i < deg; i++) {
        int eid = csr[o0 + i];
        int sn = src[eid];
        float w0 = __expf(LG[eid] - m0);
        float w1 = __expf(LG[EE + eid] - m1);
        float w2 = __expf(LG[2 * EE + eid] - m2);
        s0 += w0; s1 += w1; s2 += w2;
        const float4* ef4 = (const float4*)(ef + (size_t)eid * 12);
        float4 ea = ef4[0], eb = ef4[1], ec = ef4[2];
        float efv[12] = {ea.x, ea.y, ea.z, ea.w, eb.x, eb.y, eb.z, eb.w, ec.x, ec.y, ec.z, ec.w};
        const float* pnrow = PN + (size_t)sn * 384;
        float wk[3] = {w0, w1, w2};
#pragma unroll
        for (int k = 0; k < 3; k++) {
            float2 p = *(const float2*)(pnrow + k * 128 + c0);
            float x0 = p.x, x1 = p.y;
            const float* w = pws[k] + NFD * 128 + c0;
#pragma unroll
            for (int j = 0; j < 12; j++) {
                float2 wv = *(const float2*)(w + j * 128);
                x0 += efv[j] * wv.x; x1 += efv[j] * wv.y;
            }
            x0 = leakyf(x0); x1 = leakyf(x1);
            acc[k][0] += wk[k] * x0;
            acc[k][1] += wk[k] * x1;
        }
    }
    float sv[3] = {s0, s1, s2};
#pragma unroll
    for (int k = 0; k < 3; k++)
        *(float2*)(arow + k * 128 + c0) = make_float2(acc[k][0] / sv[k], acc[k][1] / sv[k]);
}

// ---------------- fused GRU gates + relu ----------------
__global__ void k_gru(const float* __restrict__ GI, const float* __restrict__ GH,
                      const float* __restrict__ HB, float* __restrict__ out)
{
    int idx = blockIdx.x * 256 + threadIdx.x;
    if (idx >= NN * 128) return;
    int n = idx >> 7, c = idx & 127;
    const float* gi = GI + (size_t)n * 384;
    const float* gh = GH + (size_t)n * 384;
    float ir = gi[c], iz = gi[128 + c], in = gi[256 + c];
    float hr = gh[c], hz = gh[128 + c], hn = gh[256 + c];
    float h = HB[idx];
    float r = 1.f / (1.f + __expf(-(ir + hr)));
    float z = 1.f / (1.f + __expf(-(iz + hz)));
    float nv = tanhf(in + r * hn);
    float v = (1.f - z) * nv + z * h;
    out[idx] = v > 0.f ? v : 0.f;
}

extern "C" void kernel_launch(void* const* d_in, const int* in_sizes, int n_in,
                              void* d_out, int out_size, void* d_ws, size_t ws_size,
                              hipStream_t stream)
{
    const float* nf = (const float*)d_in[0];
    const float* ef = (const float*)d_in[1];
    const float *pn_w[3], *pn_b[3], *pe1_w[3], *pe1_b[3], *pe2_w[3], *pe2_b[3], *et_w[3], *et_b[3];
    for (int k = 0; k < 3; k++) {
        int b = 2 + k * 8;
        pn_w[k] = (const float*)d_in[b + 0]; pn_b[k] = (const float*)d_in[b + 1];
        pe1_w[k] = (const float*)d_in[b + 2]; pe1_b[k] = (const float*)d_in[b + 3];
        pe2_w[k] = (const float*)d_in[b + 4]; pe2_b[k] = (const float*)d_in[b + 5];
        et_w[k] = (const float*)d_in[b + 6]; et_b[k] = (const float*)d_in[b + 7];
    }
    const float* mca_w = (const float*)d_in[26]; const float* mca_b = (const float*)d_in[27];
    const float* mcn_w = (const float*)d_in[28]; const float* mcn_b = (const float*)d_in[29];
    const float* wih = (const float*)d_in[30]; const float* whh = (const float*)d_in[31];
    const float* bih = (const float*)d_in[32]; const float* bhh = (const float*)d_in[33];
    const int* src = (const int*)d_in[34];
    const int* dst = (const int*)d_in[35];

    float* W = (float*)d_ws;
    size_t o = 0;
    float* HV = W + o;       o += (size_t)3 * NN * 128;   // [N,384] leaky node proj
    float* PNX = W + o;      o += (size_t)3 * NN * 128;   // [N,384] Pn (+b1); reused as CTX then GH
    float* QA = W + o;       o += (size_t)3 * NN;
    float* LG = W + o;       o += (size_t)3 * EE;
    float* AX = W + o;       o += (size_t)3 * NN * 128;   // [N,384] weighted sums; reused as GI
    float* CONTEXT = W + o;  o += (size_t)NN * 128;
    float* HB = W + o;       o += (size_t)NN * 128;
    int* ib = (int*)(W + o);
    int* cnt = ib;
    int* offp = ib + NN;
    int* cur = offp + NN + 1;
    int* csr = cur + NN;
    size_t need = o * 4 + (size_t)(NN * 3 + 1 + EE) * 4;
    if (ws_size < need) return;  // workspace too small: fail loudly (out stays poisoned)

    float* CTX = PNX;
    float* GI = AX;
    float* GH = PNX;

    hipMemsetAsync(cnt, 0, NN * sizeof(int), stream);

    const int ntiles = (NN + 63) / 64;
    dim3 blk(256);

    // hv_k = leaky(nf @ pn_w + pn_b); Pn_k = nf @ pe1_w[0:74] + pe1_b
    for (int k = 0; k < 3; k++) {
        gemm_k<1><<<dim3(ntiles * 2), blk, 0, stream>>>(
            nf, NFD, 0, pn_w[k], 128, pn_b[k], HV, 384, k * 128, NN, NFD, 128, (const int*)nullptr);
        gemm_k<0><<<dim3(ntiles * 2), blk, 0, stream>>>(
            nf, NFD, 0, pe1_w[k], 128, pe1_b[k], PNX, 384, k * 128, NN, NFD, 128, (const int*)nullptr);
    }
    k_qa<<<(NN + 3) / 4, blk, 0, stream>>>(HV, pe2_w[0], pe2_w[1], pe2_w[2], QA);
    k_count<<<(EE + 255) / 256, blk, 0, stream>>>(dst, cnt);
    k_scan<<<1, 1024, 0, stream>>>(cnt, offp, cur, NN);
    k_fill<<<(EE + 255) / 256, blk, 0, stream>>>(dst, cur, csr);
    k_logits<<<(EE + 3) / 4, blk, 0, stream>>>(PNX, QA, ef,
        pe1_w[0], pe1_w[1], pe1_w[2], pe2_w[0], pe2_w[1], pe2_w[2],
        pe2_b[0], pe2_b[1], pe2_b[2], src, dst, LG);
    k_aggr<<<(NN + 3) / 4, blk, 0, stream>>>(PNX, LG, ef,
        pe1_w[0], pe1_w[1], pe1_w[2], src, offp, csr, AX);
    // ctx_k = elu(A_k @ et_w + et_b) (0 for empty nodes)  -> CTX (= PNX buffer)
    for (int k = 0; k < 3; k++) {
        gemm_k<2><<<dim3(ntiles * 2), blk, 0, stream>>>(
            AX, 384, k * 128, et_w[k], 128, et_b[k], CTX, 384, k * 128, NN, 128, 128, cnt);
    }
    gemm_k<0><<<dim3(ntiles * 2), blk, 0, stream>>>(
        CTX, 384, 0, mca_w, 128, mca_b, CONTEXT, 128, 0, NN, 384, 128, (const int*)nullptr);
    gemm_k<0><<<dim3(ntiles * 2), blk, 0, stream>>>(
        HV, 384, 0, mcn_w, 128, mcn_b, HB, 128, 0, NN, 384, 128, (const int*)nullptr);
    gemm_k<0><<<dim3(ntiles * 6), blk, 0, stream>>>(
        CONTEXT, 128, 0, wih, 384, bih, GI, 384, 0, NN, 128, 384, (const int*)nullptr);
    gemm_k<0><<<dim3(ntiles * 6), blk, 0, stream>>>(
        HB, 128, 0, whh, 384, bhh, GH, 384, 0, NN, 128, 384, (const int*)nullptr);
    k_gru<<<(NN * 128 + 255) / 256, blk, 0, stream>>>(GI, GH, HB, (float*)d_out);
}

// Round 2
// 1321.378 us; speedup vs baseline: 1.0450x; 1.0450x over previous
//
#include <hip/hip_runtime.h>
#include <hip/hip_bf16.h>
#include <math.h>

#define NN 20000
#define EE 320000
#define NFD 74
#define EFD 12

__device__ __forceinline__ float leakyf(float x) { return x > 0.f ? x : 0.01f * x; }

// ================= batched 64x64-tile fp32 GEMM (4x4/thread) =================
struct GJob {
    const float* A; const float* B; const float* bias; float* C; const int* cnt;
    int a_off; int c_off;
};

// ACT: 0 none, 1 leaky, 2 elu-with-cnt-guard
template <int ACT>
__global__ __launch_bounds__(256) void gemm64(
    GJob j0, GJob j1, GJob j2,
    int lda, int ldb, int ldc, int nrows, int K, int M)
{
    GJob jb = (blockIdx.y == 0) ? j0 : ((blockIdx.y == 1) ? j1 : j2);
    const int tiles_m = (M + 63) >> 6;
    const int tn = blockIdx.x / tiles_m;
    const int tm = blockIdx.x % tiles_m;
    const int n0 = tn << 6, m0 = tm << 6;
    __shared__ float As[32][68];
    __shared__ float Bs[32][68];
    const int tid = threadIdx.x;
    const int ai = tid >> 2, aj = (tid & 3) * 8;
    const int bj = tid >> 3, bc = (tid & 7) * 8;
    const int nn4 = (tid & 15) << 2, cc4 = (tid >> 4) << 2;
    float acc[4][4];
#pragma unroll
    for (int i = 0; i < 4; i++)
#pragma unroll
        for (int j = 0; j < 4; j++) acc[i][j] = 0.f;

    for (int k0 = 0; k0 < K; k0 += 32) {
        {
            const int grow = n0 + ai;
            const bool rok = grow < nrows;
            const float* Ap = jb.A + (size_t)grow * lda + jb.a_off + k0 + aj;
#pragma unroll
            for (int r = 0; r < 8; r++) {
                int gj = k0 + aj + r;
                As[aj + r][ai] = (rok && gj < K) ? Ap[r] : 0.f;
            }
        }
        {
            const int gj = k0 + bj;
            const bool jok = gj < K;
            const float* Bp = jb.B + (size_t)gj * ldb + m0 + bc;
#pragma unroll
            for (int r = 0; r < 8; r++) {
                int gc = m0 + bc + r;
                Bs[bj][bc + r] = (jok && gc < M) ? Bp[r] : 0.f;
            }
        }
        __syncthreads();
#pragma unroll
        for (int j = 0; j < 32; j++) {
            float4 av = *(const float4*)&As[j][nn4];
            float4 bv = *(const float4*)&Bs[j][cc4];
            acc[0][0] += av.x * bv.x; acc[0][1] += av.x * bv.y; acc[0][2] += av.x * bv.z; acc[0][3] += av.x * bv.w;
            acc[1][0] += av.y * bv.x; acc[1][1] += av.y * bv.y; acc[1][2] += av.y * bv.z; acc[1][3] += av.y * bv.w;
            acc[2][0] += av.z * bv.x; acc[2][1] += av.z * bv.y; acc[2][2] += av.z * bv.z; acc[2][3] += av.z * bv.w;
            acc[3][0] += av.w * bv.x; acc[3][1] += av.w * bv.y; acc[3][2] += av.w * bv.z; acc[3][3] += av.w * bv.w;
        }
        __syncthreads();
    }
#pragma unroll
    for (int i = 0; i < 4; i++) {
        const int gr = n0 + nn4 + i;
        if (gr >= nrows) continue;
        const bool pos = (ACT != 2) || (jb.cnt[gr] > 0);
#pragma unroll
        for (int j = 0; j < 4; j++) {
            const int gc = m0 + cc4 + j;
            if (gc >= M) continue;
            float v = acc[i][j] + jb.bias[gc];
            if (ACT == 1) v = leakyf(v);
            else if (ACT == 2) v = pos ? (v > 0.f ? v : (__expf(v) - 1.f)) : 0.f;
            jb.C[(size_t)gr * ldc + jb.c_off + gc] = v;
        }
    }
}

// ================= 128x64-tile fp32 GEMM (8x4/thread) for big-M =================
// ACT: 0 none, 3 leaky-if-col<split
template <int ACT>
__global__ __launch_bounds__(256) void gemm128(
    const float* __restrict__ A, int lda, int a_off,
    const float* __restrict__ B, int ldb,
    const float* __restrict__ bias,
    float* __restrict__ C, int ldc, int c_off,
    int nrows, int K, int M, int split)
{
    const int tiles_m = (M + 63) >> 6;
    const int tn = blockIdx.x / tiles_m;
    const int tm = blockIdx.x % tiles_m;
    const int n0 = tn << 7, m0 = tm << 6;
    __shared__ __align__(16) float As[32][128];
    __shared__ __align__(16) float Bs[32][68];
    const int tid = threadIdx.x;
    const int sr = tid >> 1;            // 0..127 A row
    const int sk = (tid & 1) * 16;      // k offset
    const int br = tid >> 3;            // 0..31 B row
    const int bc = (tid & 7) * 8;       // B col
    const int rr = (tid & 15) * 4;      // acc rows rr..rr+3 and rr+64..rr+67
    const int cc = (tid >> 4) * 4;
    const bool al = ((lda | a_off) & 3) == 0;
    float acc[8][4];
#pragma unroll
    for (int i = 0; i < 8; i++)
#pragma unroll
        for (int j = 0; j < 4; j++) acc[i][j] = 0.f;

    for (int k0 = 0; k0 < K; k0 += 32) {
        {
            const int grow = n0 + sr;
            const bool rok = grow < nrows;
            const float* Ap = A + (size_t)grow * lda + a_off + k0 + sk;
#pragma unroll
            for (int r = 0; r < 16; r += 4) {
                int gj = k0 + sk + r;
                float4 v;
                if (rok && al && gj + 3 < K) {
                    v = *(const float4*)(Ap + r);
                } else {
                    v.x = (rok && gj     < K) ? Ap[r]     : 0.f;
                    v.y = (rok && gj + 1 < K) ? Ap[r + 1] : 0.f;
                    v.z = (rok && gj + 2 < K) ? Ap[r + 2] : 0.f;
                    v.w = (rok && gj + 3 < K) ? Ap[r + 3] : 0.f;
                }
                As[sk + r][sr] = v.x; As[sk + r + 1][sr] = v.y;
                As[sk + r + 2][sr] = v.z; As[sk + r + 3][sr] = v.w;
            }
        }
        {
            const int gj = k0 + br;
            const bool jok = gj < K;
            const float* Bp = B + (size_t)gj * ldb + m0 + bc;
#pragma unroll
            for (int r = 0; r < 8; r++) {
                int gc = m0 + bc + r;
                Bs[br][bc + r] = (jok && gc < M) ? Bp[r] : 0.f;
            }
        }
        __syncthreads();
#pragma unroll
        for (int kk = 0; kk < 32; kk++) {
            float4 a0 = *(const float4*)&As[kk][rr];
            float4 a1 = *(const float4*)&As[kk][rr + 64];
            float4 bv = *(const float4*)&Bs[kk][cc];
            float av[8] = {a0.x, a0.y, a0.z, a0.w, a1.x, a1.y, a1.z, a1.w};
#pragma unroll
            for (int i = 0; i < 8; i++) {
                acc[i][0] += av[i] * bv.x; acc[i][1] += av[i] * bv.y;
                acc[i][2] += av[i] * bv.z; acc[i][3] += av[i] * bv.w;
            }
        }
        __syncthreads();
    }
#pragma unroll
    for (int h = 0; h < 2; h++)
#pragma unroll
    for (int i = 0; i < 4; i++) {
        const int gr = n0 + rr + h * 64 + i;
        if (gr >= nrows) continue;
#pragma unroll
        for (int j = 0; j < 4; j++) {
            const int gc = m0 + cc + j;
            if (gc >= M) continue;
            float v = acc[h * 4 + i][j] + bias[gc];
            if (ACT == 3 && (c_off + gc) < split) v = leakyf(v);
            C[(size_t)gr * ldc + c_off + gc] = v;
        }
    }
}

// ================= weight packing =================
__global__ void k_pack(
    const float* __restrict__ pn0, const float* __restrict__ pn1, const float* __restrict__ pn2,
    const float* __restrict__ pb0, const float* __restrict__ pb1, const float* __restrict__ pb2,
    const float* __restrict__ pe0, const float* __restrict__ pe1, const float* __restrict__ pe2,
    const float* __restrict__ qb0, const float* __restrict__ qb1, const float* __restrict__ qb2,
    const float* __restrict__ wih, const float* __restrict__ whh,
    float* __restrict__ PK, float* __restrict__ PB, float* __restrict__ WG, float* __restrict__ Z512)
{
    int idx = blockIdx.x * 256 + threadIdx.x;
    const float* pnw[3] = {pn0, pn1, pn2};
    const float* pew[3] = {pe0, pe1, pe2};
    const float* pnb[3] = {pb0, pb1, pb2};
    const float* peb[3] = {qb0, qb1, qb2};
    if (idx < 131072) {
        int r = idx >> 9, c = idx & 511;
        float v;
        if (r < 128) v = (c < 384) ? wih[r * 384 + c] : 0.f;
        else {
            int rr = r - 128;
            if (c < 256) v = whh[rr * 384 + c];
            else if (c < 384) v = 0.f;
            else v = whh[rr * 384 + (c - 128)];
        }
        WG[idx] = v;
    } else if (idx < 131072 + 56832) {
        int t = idx - 131072;
        int r = t / 768, c = t - r * 768;
        int k = (c >> 7) % 3, cc = c & 127;
        PK[t] = (c < 384) ? pnw[k][r * 128 + cc] : pew[k][r * 128 + cc];
    } else if (idx < 131072 + 56832 + 768) {
        int c = idx - (131072 + 56832);
        int k = (c >> 7) % 3, cc = c & 127;
        PB[c] = (c < 384) ? pnb[k][cc] : peb[k][cc];
    } else if (idx < 131072 + 56832 + 768 + 512) {
        Z512[idx - (131072 + 56832 + 768)] = 0.f;
    }
}

// ================= qa_k[n] = hv_k[n] . w2a_k =================
__global__ __launch_bounds__(256) void k_qa(
    const float* __restrict__ HV,   // [N,768], hv at cols 0..383
    const float* __restrict__ w0, const float* __restrict__ w1, const float* __restrict__ w2,
    float* __restrict__ QA)
{
    int n = (blockIdx.x << 2) + (threadIdx.x >> 6);
    if (n >= NN) return;
    int lane = threadIdx.x & 63;
    int c0 = lane * 2;
    const float* hr = HV + (size_t)n * 768;
    const float* ws[3] = {w0, w1, w2};
#pragma unroll
    for (int k = 0; k < 3; k++) {
        float2 h = *(const float2*)(hr + k * 128 + c0);
        float2 wv = *(const float2*)(ws[k] + c0);
        float part = h.x * wv.x + h.y * wv.y;
#pragma unroll
        for (int m = 1; m < 64; m <<= 1) part += __shfl_xor(part, m, 64);
        if (lane == 0) QA[k * NN + n] = part;
    }
}

// ================= CSR build =================
__global__ void k_count(const int* __restrict__ dst, int* __restrict__ cnt)
{
    int e = blockIdx.x * 256 + threadIdx.x;
    if (e < EE) atomicAdd(&cnt[dst[e]], 1);
}

__global__ __launch_bounds__(1024) void k_scan(
    const int* __restrict__ cnt, int* __restrict__ off, int* __restrict__ cur, int n)
{
    __shared__ int warp_sums[16];
    __shared__ int s_run;
    int tid = threadIdx.x;
    int lane = tid & 63, wid = tid >> 6;
    if (tid == 0) s_run = 0;
    __syncthreads();
    for (int base = 0; base < n; base += 1024) {
        int i = base + tid;
        int v = (i < n) ? cnt[i] : 0;
        int x = v;
#pragma unroll
        for (int d = 1; d < 64; d <<= 1) { int y = __shfl_up(x, d, 64); if (lane >= d) x += y; }
        if (lane == 63) warp_sums[wid] = x;
        __syncthreads();
        if (wid == 0) {
            int wv = (lane < 16) ? warp_sums[lane] : 0;
#pragma unroll
            for (int d = 1; d < 16; d <<= 1) { int y = __shfl_up(wv, d, 64); if (lane >= d) wv += y; }
            if (lane < 16) warp_sums[lane] = wv;
        }
        __syncthreads();
        int wave_off = (wid > 0) ? warp_sums[wid - 1] : 0;
        int incl = x + wave_off;
        int run = s_run;
        int excl = run + incl - v;
        if (i < n) { off[i] = excl; cur[i] = excl; }
        __syncthreads();
        if (tid == 1023) s_run = run + incl;
        __syncthreads();
    }
    if (tid == 0) off[n] = s_run;
}

__global__ void k_fill(const int* __restrict__ dst, int* __restrict__ cur, int* __restrict__ csr)
{
    int e = blockIdx.x * 256 + threadIdx.x;
    if (e < EE) { int p = atomicAdd(&cur[dst[e]], 1); csr[p] = e; }
}

// ================= edge logits: ELG = exp(lg), SS += exp(lg) =================
// block: 128 edges; thread: 4 edges (eg+32i) x 16 chans (cg*4+32*ii)
__global__ __launch_bounds__(256) void k_logits2(
    const float* __restrict__ HP,   // [N,768], Pn at cols 384..767
    const float* __restrict__ QA,
    const float* __restrict__ ef,
    const float* __restrict__ pw0, const float* __restrict__ pw1, const float* __restrict__ pw2,
    const float* __restrict__ v0, const float* __restrict__ v1, const float* __restrict__ v2,
    const float* __restrict__ b0, const float* __restrict__ b1, const float* __restrict__ b2,
    const int* __restrict__ src, const int* __restrict__ dst,
    float* __restrict__ ELG, float* __restrict__ SS)
{
    __shared__ __align__(16) float sWE[3 * 12 * 128];
    __shared__ __align__(16) float sWB[3 * 128];
    __shared__ float sEF[128 * 12];
    const int t = threadIdx.x;
    const float* pws[3] = {pw0, pw1, pw2};
    const float* vs[3] = {v0, v1, v2};
    for (int idx = t; idx < 3 * 12 * 128; idx += 256) {
        int k = idx / 1536;
        sWE[idx] = pws[k][NFD * 128 + (idx - k * 1536)];
    }
    for (int idx = t; idx < 3 * 128; idx += 256) {
        int k = idx >> 7, c = idx & 127;
        sWB[idx] = vs[k][128 + c];
    }
    const int e0 = blockIdx.x * 128;
    for (int idx = t; idx < 128 * 12; idx += 256) {
        int e = e0 + idx / 12;
        sEF[idx] = (e < EE) ? ef[(size_t)e * 12 + (idx % 12)] : 0.f;
    }
    __syncthreads();

    const int eg = t >> 3, cg = t & 7;
    int eids[4], sns[4];
#pragma unroll
    for (int i = 0; i < 4; i++) {
        int e = e0 + eg + 32 * i;
        eids[i] = e;
        sns[i] = (e < EE) ? src[e] : 0;
    }
    float part[4][3];
    float4 acc[4][4];
#pragma unroll
    for (int k = 0; k < 3; k++) {
#pragma unroll
        for (int i = 0; i < 4; i++) {
            const float4* pr = (const float4*)(HP + (size_t)sns[i] * 768 + 384 + k * 128);
#pragma unroll
            for (int ii = 0; ii < 4; ii++) acc[i][ii] = pr[cg + 8 * ii];
        }
#pragma unroll
        for (int j = 0; j < 12; j++) {
            const float4* wrow = (const float4*)(sWE + (k * 12 + j) * 128);
            float4 w[4];
#pragma unroll
            for (int ii = 0; ii < 4; ii++) w[ii] = wrow[cg + 8 * ii];
#pragma unroll
            for (int i = 0; i < 4; i++) {
                float ev = sEF[(eg + 32 * i) * 12 + j];
#pragma unroll
                for (int ii = 0; ii < 4; ii++) {
                    acc[i][ii].x += ev * w[ii].x;
                    acc[i][ii].y += ev * w[ii].y;
                    acc[i][ii].z += ev * w[ii].z;
                    acc[i][ii].w += ev * w[ii].w;
                }
            }
        }
        float4 wb[4];
        const float4* wbp = (const float4*)(sWB + k * 128);
#pragma unroll
        for (int ii = 0; ii < 4; ii++) wb[ii] = wbp[cg + 8 * ii];
#pragma unroll
        for (int i = 0; i < 4; i++) {
            float s = 0.f;
#pragma unroll
            for (int ii = 0; ii < 4; ii++) {
                float4 x = acc[i][ii];
                s += leakyf(x.x) * wb[ii].x + leakyf(x.y) * wb[ii].y
                   + leakyf(x.z) * wb[ii].z + leakyf(x.w) * wb[ii].w;
            }
            part[i][k] = s;
        }
    }
#pragma unroll
    for (int d = 1; d < 8; d <<= 1)
#pragma unroll
        for (int i = 0; i < 4; i++)
#pragma unroll
            for (int k = 0; k < 3; k++)
                part[i][k] += __shfl_xor(part[i][k], d, 64);
    if (cg == 0) {
        float b2v[3] = {b0[0], b1[0], b2[0]};
#pragma unroll
        for (int i = 0; i < 4; i++) {
            int e = eids[i];
            if (e < EE) {
                int dn = dst[e];
#pragma unroll
                for (int k = 0; k < 3; k++) {
                    float lg = leakyf(QA[k * NN + dn] + part[i][k] + b2v[k]);
                    float ex = __expf(lg);
                    ELG[(size_t)k * EE + e] = ex;
                    atomicAdd(&SS[k * NN + dn], ex);
                }
            }
        }
    }
}

// ================= per-node aggregation: AX = sum(alpha * he1k) =================
// wave per node; lane = edge-slot (4) x ch-group (16: cg*4+{0..3} and +64)
__global__ __launch_bounds__(256) void k_aggr2(
    const float* __restrict__ HP, const float* __restrict__ ELG,
    const float* __restrict__ SS,
    const float* __restrict__ ef,
    const float* __restrict__ pw0, const float* __restrict__ pw1, const float* __restrict__ pw2,
    const int* __restrict__ src,
    const int* __restrict__ offp, const int* __restrict__ csr,
    float* __restrict__ AX)
{
    __shared__ __align__(16) float sWE[3 * 12 * 128];
    const float* pws[3] = {pw0, pw1, pw2};
    for (int idx = threadIdx.x; idx < 3 * 12 * 128; idx += 256) {
        int k = idx / 1536;
        sWE[idx] = pws[k][NFD * 128 + (idx - k * 1536)];
    }
    __syncthreads();
    int wid = threadIdx.x >> 6, lane = threadIdx.x & 63;
    int n = blockIdx.x * 4 + wid;
    if (n >= NN) return;
    int o0 = offp[n], deg = offp[n + 1] - o0;
    int sub = lane >> 4, cg = lane & 15;
    float4 acc[3][2];
#pragma unroll
    for (int k = 0; k < 3; k++)
#pragma unroll
        for (int h = 0; h < 2; h++) acc[k][h] = make_float4(0.f, 0.f, 0.f, 0.f);

    for (int b = 0; b < deg; b += 4) {
        int pos = b + sub;
        bool on = pos < deg;
        int cpos = o0 + (on ? pos : 0);
        int eid = csr[cpos];
        int sn = src[eid];
        float ew[3];
#pragma unroll
        for (int k = 0; k < 3; k++) ew[k] = on ? ELG[(size_t)k * EE + eid] : 0.f;
        const float4* efp = (const float4*)(ef + (size_t)eid * 12);
        float4 ea = efp[0], eb = efp[1], ec = efp[2];
        float efr[12] = {ea.x, ea.y, ea.z, ea.w, eb.x, eb.y, eb.z, eb.w, ec.x, ec.y, ec.z, ec.w};
#pragma unroll
        for (int k = 0; k < 3; k++) {
            const float4* pr = (const float4*)(HP + (size_t)sn * 768 + 384 + k * 128);
            float4 x0 = pr[cg], x1 = pr[cg + 16];
            const float4* wbase = (const float4*)(sWE + k * 1536);
#pragma unroll
            for (int j = 0; j < 12; j++) {
                float4 w0 = wbase[j * 32 + cg], w1 = wbase[j * 32 + cg + 16];
                x0.x += efr[j] * w0.x; x0.y += efr[j] * w0.y; x0.z += efr[j] * w0.z; x0.w += efr[j] * w0.w;
                x1.x += efr[j] * w1.x; x1.y += efr[j] * w1.y; x1.z += efr[j] * w1.z; x1.w += efr[j] * w1.w;
            }
            acc[k][0].x += ew[k] * leakyf(x0.x); acc[k][0].y += ew[k] * leakyf(x0.y);
            acc[k][0].z += ew[k] * leakyf(x0.z); acc[k][0].w += ew[k] * leakyf(x0.w);
            acc[k][1].x += ew[k] * leakyf(x1.x); acc[k][1].y += ew[k] * leakyf(x1.y);
            acc[k][1].z += ew[k] * leakyf(x1.z); acc[k][1].w += ew[k] * leakyf(x1.w);
        }
    }
#pragma unroll
    for (int d = 16; d < 64; d <<= 1) {
#pragma unroll
        for (int k = 0; k < 3; k++)
#pragma unroll
            for (int h = 0; h < 2; h++) {
                acc[k][h].x += __shfl_xor(acc[k][h].x, d, 64);
                acc[k][h].y += __shfl_xor(acc[k][h].y, d, 64);
                acc[k][h].z += __shfl_xor(acc[k][h].z, d, 64);
                acc[k][h].w += __shfl_xor(acc[k][h].w, d, 64);
            }
    }
    if (sub == 0) {
#pragma unroll
        for (int k = 0; k < 3; k++) {
            float inv = (deg > 0) ? 1.f / SS[k * NN + n] : 0.f;
            float4 r0 = acc[k][0], r1 = acc[k][1];
            r0.x *= inv; r0.y *= inv; r0.z *= inv; r0.w *= inv;
            r1.x *= inv; r1.y *= inv; r1.z *= inv; r1.w *= inv;
            *(float4*)(AX + (size_t)n * 384 + k * 128 + cg * 4) = r0;
            *(float4*)(AX + (size_t)n * 384 + k * 128 + 64 + cg * 4) = r1;
        }
    }
}

// ================= fused GRU gates + relu =================
__global__ void k_gru2(const float* __restrict__ G, const float* __restrict__ X,
                       const float* __restrict__ bih, const float* __restrict__ bhh,
                       float* __restrict__ out)
{
    int idx = blockIdx.x * 256 + threadIdx.x;
    if (idx >= NN * 128) return;
    int n = idx >> 7, c = idx & 127;
    const float* g = G + (size_t)n * 512;
    float r = 1.f / (1.f + __expf(-(g[c] + bih[c] + bhh[c])));
    float z = 1.f / (1.f + __expf(-(g[128 + c] + bih[128 + c] + bhh[128 + c])));
    float nv = tanhf(g[256 + c] + bih[256 + c] + r * (g[384 + c] + bhh[256 + c]));
    float h = X[(size_t)n * 256 + 128 + c];
    float v = (1.f - z) * nv + z * h;
    out[idx] = v > 0.f ? v : 0.f;
}

extern "C" void kernel_launch(void* const* d_in, const int* in_sizes, int n_in,
                              void* d_out, int out_size, void* d_ws, size_t ws_size,
                              hipStream_t stream)
{
    const float* nf = (const float*)d_in[0];
    const float* ef = (const float*)d_in[1];
    const float *pn_w[3], *pn_b[3], *pe1_w[3], *pe1_b[3], *pe2_w[3], *pe2_b[3], *et_w[3], *et_b[3];
    for (int k = 0; k < 3; k++) {
        int b = 2 + k * 8;
        pn_w[k] = (const float*)d_in[b + 0]; pn_b[k] = (const float*)d_in[b + 1];
        pe1_w[k] = (const float*)d_in[b + 2]; pe1_b[k] = (const float*)d_in[b + 3];
        pe2_w[k] = (const float*)d_in[b + 4]; pe2_b[k] = (const float*)d_in[b + 5];
        et_w[k] = (const float*)d_in[b + 6]; et_b[k] = (const float*)d_in[b + 7];
    }
    const float* mca_w = (const float*)d_in[26]; const float* mca_b = (const float*)d_in[27];
    const float* mcn_w = (const float*)d_in[28]; const float* mcn_b = (const float*)d_in[29];
    const float* wih = (const float*)d_in[30]; const float* whh = (const float*)d_in[31];
    const float* bih = (const float*)d_in[32]; const float* bhh = (const float*)d_in[33];
    const int* src = (const int*)d_in[34];
    const int* dst = (const int*)d_in[35];

    float* W = (float*)d_ws;
    size_t o = 0;
    float* HP = W + o;   o += (size_t)NN * 768;   // hv(0..383) | Pn->CTX(384..767); reused as G
    float* AX = W + o;   o += (size_t)NN * 384;   // weighted sums; reused as X [N,256]
    float* QA = W + o;   o += 3 * NN;
    float* ELG = W + o;  o += (size_t)3 * EE;
    float* SS = W + o;   o += 3 * NN;
    float* PK = W + o;   o += 74 * 768;
    float* PB = W + o;   o += 768;
    float* WG = W + o;   o += 256 * 512;
    float* Z512 = W + o; o += 512;
    int* cnt = (int*)(W + o);
    int* offp = cnt + NN;
    int* cur = offp + NN + 1;
    int* csr = cur + NN;
    size_t need = o * 4 + (size_t)(NN * 3 + 1 + EE) * 4;
    if (ws_size < need) return;  // fail loudly (out stays poisoned)

    float* Xb = AX;   // [N,256]
    float* Gb = HP;   // [N,512]

    hipMemsetAsync(cnt, 0, NN * sizeof(int), stream);
    hipMemsetAsync(SS, 0, 3 * NN * sizeof(float), stream);

    dim3 blk(256);
    k_pack<<<740, blk, 0, stream>>>(
        pn_w[0], pn_w[1], pn_w[2], pn_b[0], pn_b[1], pn_b[2],
        pe1_w[0], pe1_w[1], pe1_w[2], pe1_b[0], pe1_b[1], pe1_b[2],
        wih, whh, PK, PB, WG, Z512);

    const int rt128 = (NN + 127) / 128;   // 157
    const int rt64 = (NN + 63) / 64;      // 313

    // HP = [leaky(nf@pnw+b) | nf@pe1w+b]
    gemm128<3><<<dim3(rt128 * 12), blk, 0, stream>>>(
        nf, NFD, 0, PK, 768, PB, HP, 768, 0, NN, NFD, 768, 384);

    k_qa<<<(NN + 3) / 4, blk, 0, stream>>>(HP, pe2_w[0], pe2_w[1], pe2_w[2], QA);
    k_count<<<(EE + 255) / 256, blk, 0, stream>>>(dst, cnt);
    k_scan<<<1, 1024, 0, stream>>>(cnt, offp, cur, NN);
    k_fill<<<(EE + 255) / 256, blk, 0, stream>>>(dst, cur, csr);

    k_logits2<<<(EE + 127) / 128, blk, 0, stream>>>(HP, QA, ef,
        pe1_w[0], pe1_w[1], pe1_w[2], pe2_w[0], pe2_w[1], pe2_w[2],
        pe2_b[0], pe2_b[1], pe2_b[2], src, dst, ELG, SS);

    k_aggr2<<<(NN + 3) / 4, blk, 0, stream>>>(HP, ELG, SS, ef,
        pe1_w[0], pe1_w[1], pe1_w[2], src, offp, csr, AX);

    // ctx_k = elu(AX_k @ et_w + b) -> HP cols 384.. (batched over k)
    {
        GJob j0 = {AX, et_w[0], et_b[0], HP, cnt, 0 * 128, 384 + 0 * 128};
        GJob j1 = {AX, et_w[1], et_b[1], HP, cnt, 1 * 128, 384 + 1 * 128};
        GJob j2 = {AX, et_w[2], et_b[2], HP, cnt, 2 * 128, 384 + 2 * 128};
        gemm64<2><<<dim3(rt64 * 2, 3), blk, 0, stream>>>(j0, j1, j2, 384, 128, 768, NN, 128, 128);
    }
    // X[:,0:128] = ctx@mca_w+b ; X[:,128:256] = hv@mcn_w+b (batched)
    {
        GJob j0 = {HP, mca_w, mca_b, Xb, nullptr, 384, 0};
        GJob j1 = {HP, mcn_w, mcn_b, Xb, nullptr, 0, 128};
        gemm64<0><<<dim3(rt64 * 2, 2), blk, 0, stream>>>(j0, j1, j1, 768, 128, 256, NN, 384, 128);
    }
    // G = X @ WG  (r|z|in|hn)
    gemm128<0><<<dim3(rt128 * 8), blk, 0, stream>>>(
        Xb, 256, 0, WG, 512, Z512, Gb, 512, 0, NN, 256, 512, 0);

    k_gru2<<<(NN * 128 + 255) / 256, blk, 0, stream>>>(Gb, Xb, bih, bhh, (float*)d_out);
}

// Round 3
// 735.781 us; speedup vs baseline: 1.8767x; 1.7959x over previous
//
#include <hip/hip_runtime.h>
#include <hip/hip_bf16.h>
#include <math.h>

#define NN 20000
#define EE 320000
#define NFD 74
#define EFD 12

__device__ __forceinline__ float leakyf(float x) { return x > 0.f ? x : 0.01f * x; }

// ================= batched 128x64-tile fp32 GEMM (8x4/thread) =================
struct GJob {
    const float* A; const float* B; const float* bias; float* C; const int* offp;
    int a_off; int c_off;
};

// ACT: 0 none, 2 elu with empty-node guard (offp), 3 leaky-if-col<split
template <int ACT>
__global__ __launch_bounds__(256) void gemm128j(
    GJob j0, GJob j1, GJob j2,
    int lda, int ldb, int ldc, int nrows, int K, int M, int split)
{
    GJob jb = (blockIdx.y == 0) ? j0 : ((blockIdx.y == 1) ? j1 : j2);
    const int tiles_m = (M + 63) >> 6;
    const int tn = blockIdx.x / tiles_m;
    const int tm = blockIdx.x % tiles_m;
    const int n0 = tn << 7, m0 = tm << 6;
    __shared__ __align__(16) float As[32][128];
    __shared__ __align__(16) float Bs[32][68];
    const int tid = threadIdx.x;
    const int sr = tid >> 1;            // 0..127 A row
    const int sk = (tid & 1) * 16;      // k offset
    const int br = tid >> 3;            // 0..31 B row
    const int bc = (tid & 7) * 8;       // B col
    const int rr = (tid & 15) * 4;      // acc rows rr..rr+3 and rr+64..rr+67
    const int cc = (tid >> 4) * 4;
    const bool al = ((lda | jb.a_off) & 3) == 0;
    float acc[8][4];
#pragma unroll
    for (int i = 0; i < 8; i++)
#pragma unroll
        for (int j = 0; j < 4; j++) acc[i][j] = 0.f;

    for (int k0 = 0; k0 < K; k0 += 32) {
        {
            const int grow = n0 + sr;
            const bool rok = grow < nrows;
            const float* Ap = jb.A + (size_t)grow * lda + jb.a_off + k0 + sk;
#pragma unroll
            for (int r = 0; r < 16; r += 4) {
                int gj = k0 + sk + r;
                float4 v;
                if (rok && al && gj + 3 < K) {
                    v = *(const float4*)(Ap + r);
                } else {
                    v.x = (rok && gj     < K) ? Ap[r]     : 0.f;
                    v.y = (rok && gj + 1 < K) ? Ap[r + 1] : 0.f;
                    v.z = (rok && gj + 2 < K) ? Ap[r + 2] : 0.f;
                    v.w = (rok && gj + 3 < K) ? Ap[r + 3] : 0.f;
                }
                As[sk + r][sr] = v.x; As[sk + r + 1][sr] = v.y;
                As[sk + r + 2][sr] = v.z; As[sk + r + 3][sr] = v.w;
            }
        }
        {
            const int gj = k0 + br;
            const bool jok = gj < K;
            const float* Bp = jb.B + (size_t)gj * ldb + m0 + bc;
#pragma unroll
            for (int r = 0; r < 8; r++) {
                int gc = m0 + bc + r;
                Bs[br][bc + r] = (jok && gc < M) ? Bp[r] : 0.f;
            }
        }
        __syncthreads();
#pragma unroll
        for (int kk = 0; kk < 32; kk++) {
            float4 a0 = *(const float4*)&As[kk][rr];
            float4 a1 = *(const float4*)&As[kk][rr + 64];
            float4 bv = *(const float4*)&Bs[kk][cc];
            float av[8] = {a0.x, a0.y, a0.z, a0.w, a1.x, a1.y, a1.z, a1.w};
#pragma unroll
            for (int i = 0; i < 8; i++) {
                acc[i][0] += av[i] * bv.x; acc[i][1] += av[i] * bv.y;
                acc[i][2] += av[i] * bv.z; acc[i][3] += av[i] * bv.w;
            }
        }
        __syncthreads();
    }
#pragma unroll
    for (int h = 0; h < 2; h++)
#pragma unroll
    for (int i = 0; i < 4; i++) {
        const int gr = n0 + rr + h * 64 + i;
        if (gr >= nrows) continue;
        bool pos = true;
        if (ACT == 2) pos = jb.offp[gr + 1] > jb.offp[gr];
#pragma unroll
        for (int j = 0; j < 4; j++) {
            const int gc = m0 + cc + j;
            if (gc >= M) continue;
            float v = acc[h * 4 + i][j] + jb.bias[gc];
            if (ACT == 2) v = pos ? (v > 0.f ? v : (__expf(v) - 1.f)) : 0.f;
            if (ACT == 3 && (jb.c_off + gc) < split) v = leakyf(v);
            jb.C[(size_t)gr * ldc + jb.c_off + gc] = v;
        }
    }
}

// ================= weight packing =================
__global__ void k_pack(
    const float* __restrict__ pn0, const float* __restrict__ pn1, const float* __restrict__ pn2,
    const float* __restrict__ pb0, const float* __restrict__ pb1, const float* __restrict__ pb2,
    const float* __restrict__ pe0, const float* __restrict__ pe1, const float* __restrict__ pe2,
    const float* __restrict__ qb0, const float* __restrict__ qb1, const float* __restrict__ qb2,
    const float* __restrict__ wih, const float* __restrict__ whh,
    float* __restrict__ PK, float* __restrict__ PB, float* __restrict__ WG, float* __restrict__ Z512)
{
    int idx = blockIdx.x * 256 + threadIdx.x;
    const float* pnw[3] = {pn0, pn1, pn2};
    const float* pew[3] = {pe0, pe1, pe2};
    const float* pnb[3] = {pb0, pb1, pb2};
    const float* peb[3] = {qb0, qb1, qb2};
    if (idx < 131072) {
        int r = idx >> 9, c = idx & 511;
        float v;
        if (r < 128) v = (c < 384) ? wih[r * 384 + c] : 0.f;
        else {
            int rr = r - 128;
            if (c < 256) v = whh[rr * 384 + c];
            else if (c < 384) v = 0.f;
            else v = whh[rr * 384 + (c - 128)];
        }
        WG[idx] = v;
    } else if (idx < 131072 + 56832) {
        int t = idx - 131072;
        int r = t / 768, c = t - r * 768;
        int k = (c >> 7) % 3, cc = c & 127;
        PK[t] = (c < 384) ? pnw[k][r * 128 + cc] : pew[k][r * 128 + cc];
    } else if (idx < 131072 + 56832 + 768) {
        int c = idx - (131072 + 56832);
        int k = (c >> 7) % 3, cc = c & 127;
        PB[c] = (c < 384) ? pnb[k][cc] : peb[k][cc];
    } else if (idx < 131072 + 56832 + 768 + 512) {
        Z512[idx - (131072 + 56832 + 768)] = 0.f;
    }
}

// ================= CSR build =================
__global__ void k_count(const int* __restrict__ dst, int* __restrict__ cnt)
{
    int e = blockIdx.x * 256 + threadIdx.x;
    if (e < EE) atomicAdd(&cnt[dst[e]], 1);
}

__global__ __launch_bounds__(1024) void k_scan(
    const int* __restrict__ cnt, int* __restrict__ off, int* __restrict__ cur, int n)
{
    __shared__ int warp_sums[16];
    __shared__ int s_run;
    int tid = threadIdx.x;
    int lane = tid & 63, wid = tid >> 6;
    if (tid == 0) s_run = 0;
    __syncthreads();
    for (int base = 0; base < n; base += 1024) {
        int i = base + tid;
        int v = (i < n) ? cnt[i] : 0;
        int x = v;
#pragma unroll
        for (int d = 1; d < 64; d <<= 1) { int y = __shfl_up(x, d, 64); if (lane >= d) x += y; }
        if (lane == 63) warp_sums[wid] = x;
        __syncthreads();
        if (wid == 0) {
            int wv = (lane < 16) ? warp_sums[lane] : 0;
#pragma unroll
            for (int d = 1; d < 16; d <<= 1) { int y = __shfl_up(wv, d, 64); if (lane >= d) wv += y; }
            if (lane < 16) warp_sums[lane] = wv;
        }
        __syncthreads();
        int wave_off = (wid > 0) ? warp_sums[wid - 1] : 0;
        int incl = x + wave_off;
        int run = s_run;
        int excl = run + incl - v;
        if (i < n) { off[i] = excl; cur[i] = excl; }
        __syncthreads();
        if (tid == 1023) s_run = run + incl;
        __syncthreads();
    }
    if (tid == 0) off[n] = s_run;
}

__global__ void k_fill(const int* __restrict__ dst, int* __restrict__ cur, int* __restrict__ csr)
{
    int e = blockIdx.x * 256 + threadIdx.x;
    if (e < EE) { int p = atomicAdd(&cur[dst[e]], 1); csr[p] = e; }
}

// ================= fused edge pipeline: wave per (node, branch) =================
// lane = er(4 edge slots, bits 4-5) x cg(16 ch-groups, bits 0-3); 8 ch per lane.
// Computes qa, he1k, logits, softmax (unnormalized exp), weighted sum, divide.
__global__ __launch_bounds__(256) void k_fused(
    const float* __restrict__ HP,   // [N,768]: hv | Pn
    const float* __restrict__ ef,
    const float* __restrict__ pw0, const float* __restrict__ pw1, const float* __restrict__ pw2,
    const float* __restrict__ v0, const float* __restrict__ v1, const float* __restrict__ v2,
    const float* __restrict__ b20, const float* __restrict__ b21, const float* __restrict__ b22,
    const int* __restrict__ src,
    const int* __restrict__ offp, const int* __restrict__ csr,
    float* __restrict__ AX)
{
    int wid = blockIdx.x * 4 + (threadIdx.x >> 6);
    int n = wid / 3;
    int k = wid - n * 3;
    if (n >= NN) return;
    int lane = threadIdx.x & 63;
    int er = lane >> 4, cg = lane & 15;
    const int c4 = cg * 4;
    const float* pw = (k == 0) ? pw0 : (k == 1) ? pw1 : pw2;
    const float* vv = (k == 0) ? v0 : (k == 1) ? v1 : v2;
    const float b2 = ((k == 0) ? b20 : (k == 1) ? b21 : b22)[0];

    // persistent edge-weight slice in registers: rows j, channels c4..c4+3, 64+c4..64+c4+3
    float4 Wr[12][2];
#pragma unroll
    for (int j = 0; j < 12; j++) {
        Wr[j][0] = *(const float4*)(pw + (NFD + j) * 128 + c4);
        Wr[j][1] = *(const float4*)(pw + (NFD + j) * 128 + 64 + c4);
    }
    float4 wb0 = *(const float4*)(vv + 128 + c4);
    float4 wb1 = *(const float4*)(vv + 128 + 64 + c4);

    // qa = hv_k[n] . w2a
    float qa;
    {
        float4 wa0 = *(const float4*)(vv + c4);
        float4 wa1 = *(const float4*)(vv + 64 + c4);
        const float* hr = HP + (size_t)n * 768 + k * 128;
        float4 h0 = *(const float4*)(hr + c4);
        float4 h1 = *(const float4*)(hr + 64 + c4);
        qa = h0.x * wa0.x + h0.y * wa0.y + h0.z * wa0.z + h0.w * wa0.w
           + h1.x * wa1.x + h1.y * wa1.y + h1.z * wa1.z + h1.w * wa1.w;
#pragma unroll
        for (int d = 1; d < 16; d <<= 1) qa += __shfl_xor(qa, d, 64);
    }

    const int o0 = offp[n];
    const int deg = offp[n + 1] - o0;
    float4 a0 = make_float4(0.f, 0.f, 0.f, 0.f);
    float4 a1 = make_float4(0.f, 0.f, 0.f, 0.f);
    float s = 0.f;

    for (int b = 0; b < deg; b += 4) {
        int pos = b + er;
        bool on = pos < deg;
        int eid = csr[o0 + (on ? pos : 0)];
        int sn = src[eid];
        const float4* efp = (const float4*)(ef + (size_t)eid * 12);
        float4 ea = efp[0], ebv = efp[1], ecv = efp[2];
        float efr[12] = {ea.x, ea.y, ea.z, ea.w, ebv.x, ebv.y, ebv.z, ebv.w,
                         ecv.x, ecv.y, ecv.z, ecv.w};
        const float* pr = HP + (size_t)sn * 768 + 384 + k * 128;
        float4 x0 = *(const float4*)(pr + c4);
        float4 x1 = *(const float4*)(pr + 64 + c4);
#pragma unroll
        for (int j = 0; j < 12; j++) {
            float e = efr[j];
            x0.x += e * Wr[j][0].x; x0.y += e * Wr[j][0].y;
            x0.z += e * Wr[j][0].z; x0.w += e * Wr[j][0].w;
            x1.x += e * Wr[j][1].x; x1.y += e * Wr[j][1].y;
            x1.z += e * Wr[j][1].z; x1.w += e * Wr[j][1].w;
        }
        x0.x = leakyf(x0.x); x0.y = leakyf(x0.y); x0.z = leakyf(x0.z); x0.w = leakyf(x0.w);
        x1.x = leakyf(x1.x); x1.y = leakyf(x1.y); x1.z = leakyf(x1.z); x1.w = leakyf(x1.w);
        float dd = x0.x * wb0.x + x0.y * wb0.y + x0.z * wb0.z + x0.w * wb0.w
                 + x1.x * wb1.x + x1.y * wb1.y + x1.z * wb1.z + x1.w * wb1.w;
#pragma unroll
        for (int d = 1; d < 16; d <<= 1) dd += __shfl_xor(dd, d, 64);
        float ex = on ? __expf(leakyf(qa + dd + b2)) : 0.f;
        a0.x += ex * x0.x; a0.y += ex * x0.y; a0.z += ex * x0.z; a0.w += ex * x0.w;
        a1.x += ex * x1.x; a1.y += ex * x1.y; a1.z += ex * x1.z; a1.w += ex * x1.w;
        s += ex;
    }
#pragma unroll
    for (int d = 16; d < 64; d <<= 1) {
        a0.x += __shfl_xor(a0.x, d, 64); a0.y += __shfl_xor(a0.y, d, 64);
        a0.z += __shfl_xor(a0.z, d, 64); a0.w += __shfl_xor(a0.w, d, 64);
        a1.x += __shfl_xor(a1.x, d, 64); a1.y += __shfl_xor(a1.y, d, 64);
        a1.z += __shfl_xor(a1.z, d, 64); a1.w += __shfl_xor(a1.w, d, 64);
        s += __shfl_xor(s, d, 64);
    }
    if (er == 0) {
        float inv = (deg > 0) ? 1.f / s : 0.f;
        a0.x *= inv; a0.y *= inv; a0.z *= inv; a0.w *= inv;
        a1.x *= inv; a1.y *= inv; a1.z *= inv; a1.w *= inv;
        float* arow = AX + (size_t)n * 384 + k * 128;
        *(float4*)(arow + c4) = a0;
        *(float4*)(arow + 64 + c4) = a1;
    }
}

// ================= fused GRU gates + relu =================
__global__ void k_gru2(const float* __restrict__ G, const float* __restrict__ X,
                       const float* __restrict__ bih, const float* __restrict__ bhh,
                       float* __restrict__ out)
{
    int idx = blockIdx.x * 256 + threadIdx.x;
    if (idx >= NN * 128) return;
    int n = idx >> 7, c = idx & 127;
    const float* g = G + (size_t)n * 512;
    float r = 1.f / (1.f + __expf(-(g[c] + bih[c] + bhh[c])));
    float z = 1.f / (1.f + __expf(-(g[128 + c] + bih[128 + c] + bhh[128 + c])));
    float nv = tanhf(g[256 + c] + bih[256 + c] + r * (g[384 + c] + bhh[256 + c]));
    float h = X[(size_t)n * 256 + 128 + c];
    float v = (1.f - z) * nv + z * h;
    out[idx] = v > 0.f ? v : 0.f;
}

extern "C" void kernel_launch(void* const* d_in, const int* in_sizes, int n_in,
                              void* d_out, int out_size, void* d_ws, size_t ws_size,
                              hipStream_t stream)
{
    const float* nf = (const float*)d_in[0];
    const float* ef = (const float*)d_in[1];
    const float *pn_w[3], *pn_b[3], *pe1_w[3], *pe1_b[3], *pe2_w[3], *pe2_b[3], *et_w[3], *et_b[3];
    for (int k = 0; k < 3; k++) {
        int b = 2 + k * 8;
        pn_w[k] = (const float*)d_in[b + 0]; pn_b[k] = (const float*)d_in[b + 1];
        pe1_w[k] = (const float*)d_in[b + 2]; pe1_b[k] = (const float*)d_in[b + 3];
        pe2_w[k] = (const float*)d_in[b + 4]; pe2_b[k] = (const float*)d_in[b + 5];
        et_w[k] = (const float*)d_in[b + 6]; et_b[k] = (const float*)d_in[b + 7];
    }
    const float* mca_w = (const float*)d_in[26]; const float* mca_b = (const float*)d_in[27];
    const float* mcn_w = (const float*)d_in[28]; const float* mcn_b = (const float*)d_in[29];
    const float* wih = (const float*)d_in[30]; const float* whh = (const float*)d_in[31];
    const float* bih = (const float*)d_in[32]; const float* bhh = (const float*)d_in[33];
    const int* src = (const int*)d_in[34];
    const int* dst = (const int*)d_in[35];

    float* W = (float*)d_ws;
    size_t o = 0;
    float* HP = W + o;   o += (size_t)NN * 768;   // hv(0..383) | Pn->CTX(384..767); reused as G
    float* AX = W + o;   o += (size_t)NN * 384;   // weighted sums; reused as X [N,256]
    float* PK = W + o;   o += 74 * 768;
    float* PB = W + o;   o += 768;
    float* WG = W + o;   o += 256 * 512;
    float* Z512 = W + o; o += 512;
    int* cnt = (int*)(W + o);
    int* offp = cnt + NN;
    int* cur = offp + NN + 1;
    int* csr = cur + NN;
    size_t need = o * 4 + (size_t)(NN * 3 + 1 + EE) * 4;
    if (ws_size < need) return;  // fail loudly (out stays poisoned)

    float* Xb = AX;   // [N,256]
    float* Gb = HP;   // [N,512]

    hipMemsetAsync(cnt, 0, NN * sizeof(int), stream);

    dim3 blk(256);
    k_pack<<<740, blk, 0, stream>>>(
        pn_w[0], pn_w[1], pn_w[2], pn_b[0], pn_b[1], pn_b[2],
        pe1_w[0], pe1_w[1], pe1_w[2], pe1_b[0], pe1_b[1], pe1_b[2],
        wih, whh, PK, PB, WG, Z512);

    const int rt128 = (NN + 127) / 128;   // 157

    // HP = [leaky(nf@pnw+b) | nf@pe1w+b]
    {
        GJob j = {nf, PK, PB, HP, nullptr, 0, 0};
        gemm128j<3><<<dim3(rt128 * 12), blk, 0, stream>>>(j, j, j, NFD, 768, 768, NN, NFD, 768, 384);
    }

    k_count<<<(EE + 255) / 256, blk, 0, stream>>>(dst, cnt);
    k_scan<<<1, 1024, 0, stream>>>(cnt, offp, cur, NN);
    k_fill<<<(EE + 255) / 256, blk, 0, stream>>>(dst, cur, csr);

    // fused: qa + he1k + logits + softmax + weighted aggregation
    k_fused<<<(NN * 3) / 4, blk, 0, stream>>>(HP, ef,
        pe1_w[0], pe1_w[1], pe1_w[2], pe2_w[0], pe2_w[1], pe2_w[2],
        pe2_b[0], pe2_b[1], pe2_b[2], src, offp, csr, AX);

    // ctx_k = elu(AX_k @ et_w + b) -> HP cols 384.. (batched over k, empty-node guard)
    {
        GJob j0 = {AX, et_w[0], et_b[0], HP, offp, 0 * 128, 384 + 0 * 128};
        GJob j1 = {AX, et_w[1], et_b[1], HP, offp, 1 * 128, 384 + 1 * 128};
        GJob j2 = {AX, et_w[2], et_b[2], HP, offp, 2 * 128, 384 + 2 * 128};
        gemm128j<2><<<dim3(rt128 * 2, 3), blk, 0, stream>>>(j0, j1, j2, 384, 128, 768, NN, 128, 128, 0);
    }
    // X[:,0:128] = ctx@mca_w+b ; X[:,128:256] = hv@mcn_w+b (batched)
    {
        GJob j0 = {HP, mca_w, mca_b, Xb, nullptr, 384, 0};
        GJob j1 = {HP, mcn_w, mcn_b, Xb, nullptr, 0, 128};
        gemm128j<0><<<dim3(rt128 * 2, 2), blk, 0, stream>>>(j0, j1, j1, 768, 128, 256, NN, 384, 128, 0);
    }
    // G = X @ WG  (r|z|in|hn)
    {
        GJob j = {Xb, WG, Z512, Gb, nullptr, 0, 0};
        gemm128j<0><<<dim3(rt128 * 8), blk, 0, stream>>>(j, j, j, 256, 512, 512, NN, 256, 512, 0);
    }

    k_gru2<<<(NN * 128 + 255) / 256, blk, 0, stream>>>(Gb, Xb, bih, bhh, (float*)d_out);
}

// Round 6
// 664.171 us; speedup vs baseline: 2.0791x; 1.1078x over previous
//
#include <hip/hip_runtime.h>
#include <hip/hip_bf16.h>
#include <math.h>

#define NN 20000
#define EE 320000
#define NFD 74
#define EFD 12

__device__ __forceinline__ float leakyf(float x) { return x > 0.f ? x : 0.01f * x; }

// ================= batched 128x128-tile fp32 GEMM (8x8/thread) =================
struct GJob {
    const float* A; const float* B; const float* bias; float* C; const int* offp;
    int a_off; int c_off;
};

// ACT: 0 none, 2 elu with empty-node guard (offp), 3 leaky-if-col<split
template <int ACT>
__global__ __launch_bounds__(256) void gemm256(
    GJob j0, GJob j1, GJob j2,
    int lda, int ldb, int ldc, int nrows, int K, int M, int split)
{
    GJob jb = (blockIdx.y == 0) ? j0 : ((blockIdx.y == 1) ? j1 : j2);
    const int tiles_m = (M + 127) >> 7;
    const int tn = blockIdx.x / tiles_m;
    const int tm = blockIdx.x % tiles_m;
    const int n0 = tn << 7, m0 = tm << 7;
    __shared__ __align__(16) float As[32][128];
    __shared__ __align__(16) float Bs[32][132];
    const int tid = threadIdx.x;
    const int sr = tid >> 1;            // 0..127 A row
    const int sk = (tid & 1) * 16;      // k offset within 32
    const int br = tid >> 3;            // 0..31 B k-row
    const int bc = (tid & 7) * 16;      // B col
    const int rr = (tid & 15) * 4;      // acc rows rr..rr+3, rr+64..rr+67
    const int cc = (tid >> 4) * 4;      // acc cols cc..cc+3, cc+64..cc+67
    const bool al = ((lda | jb.a_off) & 3) == 0;
    float acc[8][8];
#pragma unroll
    for (int i = 0; i < 8; i++)
#pragma unroll
        for (int j = 0; j < 8; j++) acc[i][j] = 0.f;

    for (int k0 = 0; k0 < K; k0 += 32) {
        {
            const int grow = n0 + sr;
            const bool rok = grow < nrows;
            const float* Ap = jb.A + (size_t)grow * lda + jb.a_off + k0 + sk;
#pragma unroll
            for (int r = 0; r < 16; r += 4) {
                int gj = k0 + sk + r;
                float4 v;
                if (rok && al && gj + 3 < K) {
                    v = *(const float4*)(Ap + r);
                } else {
                    v.x = (rok && gj     < K) ? Ap[r]     : 0.f;
                    v.y = (rok && gj + 1 < K) ? Ap[r + 1] : 0.f;
                    v.z = (rok && gj + 2 < K) ? Ap[r + 2] : 0.f;
                    v.w = (rok && gj + 3 < K) ? Ap[r + 3] : 0.f;
                }
                As[sk + r][sr] = v.x; As[sk + r + 1][sr] = v.y;
                As[sk + r + 2][sr] = v.z; As[sk + r + 3][sr] = v.w;
            }
        }
        {
            const int gj = k0 + br;
            const bool jok = gj < K;
            const float* Bp = jb.B + (size_t)gj * ldb + m0 + bc;
#pragma unroll
            for (int r = 0; r < 16; r += 4) {
                float4 v = make_float4(0.f, 0.f, 0.f, 0.f);
                if (jok) v = *(const float4*)(Bp + r);
                *(float4*)&Bs[br][bc + r] = v;
            }
        }
        __syncthreads();
#pragma unroll
        for (int kk = 0; kk < 32; kk++) {
            float4 a0 = *(const float4*)&As[kk][rr];
            float4 a1 = *(const float4*)&As[kk][rr + 64];
            float4 b0 = *(const float4*)&Bs[kk][cc];
            float4 b1 = *(const float4*)&Bs[kk][cc + 64];
            float av[8] = {a0.x, a0.y, a0.z, a0.w, a1.x, a1.y, a1.z, a1.w};
            float bv[8] = {b0.x, b0.y, b0.z, b0.w, b1.x, b1.y, b1.z, b1.w};
#pragma unroll
            for (int i = 0; i < 8; i++)
#pragma unroll
                for (int j = 0; j < 8; j++)
                    acc[i][j] += av[i] * bv[j];
        }
        __syncthreads();
    }
#pragma unroll
    for (int h = 0; h < 2; h++)
#pragma unroll
    for (int i = 0; i < 4; i++) {
        const int gr = n0 + rr + h * 64 + i;
        if (gr >= nrows) continue;
        bool pos = true;
        if (ACT == 2) pos = jb.offp[gr + 1] > jb.offp[gr];
        float* Crow = jb.C + (size_t)gr * ldc + jb.c_off;
#pragma unroll
        for (int g2 = 0; g2 < 2; g2++) {
            const int gc = m0 + cc + g2 * 64;   // GLOBAL column (fix: include m0)
            if (gc >= M) continue;
            float4 v;
            float* a = &acc[h * 4 + i][g2 * 4];
            v.x = a[0] + jb.bias[gc + 0];
            v.y = a[1] + jb.bias[gc + 1];
            v.z = a[2] + jb.bias[gc + 2];
            v.w = a[3] + jb.bias[gc + 3];
            if (ACT == 2) {
                v.x = pos ? (v.x > 0.f ? v.x : (__expf(v.x) - 1.f)) : 0.f;
                v.y = pos ? (v.y > 0.f ? v.y : (__expf(v.y) - 1.f)) : 0.f;
                v.z = pos ? (v.z > 0.f ? v.z : (__expf(v.z) - 1.f)) : 0.f;
                v.w = pos ? (v.w > 0.f ? v.w : (__expf(v.w) - 1.f)) : 0.f;
            }
            if (ACT == 3) {
                if (jb.c_off + gc + 0 < split) v.x = leakyf(v.x);
                if (jb.c_off + gc + 1 < split) v.y = leakyf(v.y);
                if (jb.c_off + gc + 2 < split) v.z = leakyf(v.z);
                if (jb.c_off + gc + 3 < split) v.w = leakyf(v.w);
            }
            *(float4*)(Crow + gc) = v;
        }
    }
}

// ================= weight packing =================
__global__ void k_pack(
    const float* __restrict__ pn0, const float* __restrict__ pn1, const float* __restrict__ pn2,
    const float* __restrict__ pb0, const float* __restrict__ pb1, const float* __restrict__ pb2,
    const float* __restrict__ pe0, const float* __restrict__ pe1, const float* __restrict__ pe2,
    const float* __restrict__ qb0, const float* __restrict__ qb1, const float* __restrict__ qb2,
    const float* __restrict__ wih, const float* __restrict__ whh,
    float* __restrict__ PK, float* __restrict__ PB, float* __restrict__ WG, float* __restrict__ Z512)
{
    int idx = blockIdx.x * 256 + threadIdx.x;
    const float* pnw[3] = {pn0, pn1, pn2};
    const float* pew[3] = {pe0, pe1, pe2};
    const float* pnb[3] = {pb0, pb1, pb2};
    const float* peb[3] = {qb0, qb1, qb2};
    if (idx < 131072) {
        int r = idx >> 9, c = idx & 511;
        float v;
        if (r < 128) v = (c < 384) ? wih[r * 384 + c] : 0.f;
        else {
            int rr = r - 128;
            if (c < 256) v = whh[rr * 384 + c];
            else if (c < 384) v = 0.f;
            else v = whh[rr * 384 + (c - 128)];
        }
        WG[idx] = v;
    } else if (idx < 131072 + 56832) {
        int t = idx - 131072;
        int r = t / 768, c = t - r * 768;
        int k = (c >> 7) % 3, cc = c & 127;
        PK[t] = (c < 384) ? pnw[k][r * 128 + cc] : pew[k][r * 128 + cc];
    } else if (idx < 131072 + 56832 + 768) {
        int c = idx - (131072 + 56832);
        int k = (c >> 7) % 3, cc = c & 127;
        PB[c] = (c < 384) ? pnb[k][cc] : peb[k][cc];
    } else if (idx < 131072 + 56832 + 768 + 512) {
        Z512[idx - (131072 + 56832 + 768)] = 0.f;
    }
}

// ================= CSR build =================
__global__ void k_count(const int* __restrict__ dst, int* __restrict__ cnt)
{
    int e = blockIdx.x * 256 + threadIdx.x;
    if (e < EE) atomicAdd(&cnt[dst[e]], 1);
}

__global__ __launch_bounds__(1024) void k_scan(
    const int* __restrict__ cnt, int* __restrict__ off, int* __restrict__ cur, int n)
{
    __shared__ int warp_sums[16];
    __shared__ int s_run;
    int tid = threadIdx.x;
    int lane = tid & 63, wid = tid >> 6;
    if (tid == 0) s_run = 0;
    __syncthreads();
    for (int base = 0; base < n; base += 1024) {
        int i = base + tid;
        int v = (i < n) ? cnt[i] : 0;
        int x = v;
#pragma unroll
        for (int d = 1; d < 64; d <<= 1) { int y = __shfl_up(x, d, 64); if (lane >= d) x += y; }
        if (lane == 63) warp_sums[wid] = x;
        __syncthreads();
        if (wid == 0) {
            int wv = (lane < 16) ? warp_sums[lane] : 0;
#pragma unroll
            for (int d = 1; d < 16; d <<= 1) { int y = __shfl_up(wv, d, 64); if (lane >= d) wv += y; }
            if (lane < 16) warp_sums[lane] = wv;
        }
        __syncthreads();
        int wave_off = (wid > 0) ? warp_sums[wid - 1] : 0;
        int incl = x + wave_off;
        int run = s_run;
        int excl = run + incl - v;
        if (i < n) { off[i] = excl; cur[i] = excl; }
        __syncthreads();
        if (tid == 1023) s_run = run + incl;
        __syncthreads();
    }
    if (tid == 0) off[n] = s_run;
}

// fill: materialize src-per-slot and CSR-ordered edge features (kills two
// dependent-load hops and 3x random ef reads in k_fused)
__global__ void k_fill(const int* __restrict__ dst, const int* __restrict__ src,
                       const float* __restrict__ ef,
                       int* __restrict__ cur, int* __restrict__ csr_src,
                       float* __restrict__ EFC)
{
    int e = blockIdx.x * 256 + threadIdx.x;
    if (e < EE) {
        int p = atomicAdd(&cur[dst[e]], 1);
        csr_src[p] = src[e];
        const float4* s = (const float4*)(ef + (size_t)e * 12);
        float4* d = (float4*)(EFC + (size_t)p * 12);
        float4 v0 = s[0], v1 = s[1], v2 = s[2];
        d[0] = v0; d[1] = v1; d[2] = v2;
    }
}

// ================= fused edge pipeline: wave per (node, branch) =================
// lane = er(4 edge slots) x cg(16 ch-groups); 8 ch per lane; 8 edges in flight.
__global__ __launch_bounds__(256) void k_fused(
    const float* __restrict__ HP,   // [N,768]: hv | Pn
    const float* __restrict__ EFC,  // [E,12] CSR-ordered edge feats
    const float* __restrict__ pw0, const float* __restrict__ pw1, const float* __restrict__ pw2,
    const float* __restrict__ v0, const float* __restrict__ v1, const float* __restrict__ v2,
    const float* __restrict__ b20, const float* __restrict__ b21, const float* __restrict__ b22,
    const int* __restrict__ csr_src,
    const int* __restrict__ offp,
    float* __restrict__ AX)
{
    int wid = blockIdx.x * 4 + (threadIdx.x >> 6);
    int n = wid / 3;
    int k = wid - n * 3;
    if (n >= NN) return;
    int lane = threadIdx.x & 63;
    int er = lane >> 4, cg = lane & 15;
    const int c4 = cg * 4;
    const float* pw = (k == 0) ? pw0 : (k == 1) ? pw1 : pw2;
    const float* vv = (k == 0) ? v0 : (k == 1) ? v1 : v2;
    const float b2 = ((k == 0) ? b20 : (k == 1) ? b21 : b22)[0];

    // persistent edge-weight slice in registers
    float4 Wr[12][2];
#pragma unroll
    for (int j = 0; j < 12; j++) {
        Wr[j][0] = *(const float4*)(pw + (NFD + j) * 128 + c4);
        Wr[j][1] = *(const float4*)(pw + (NFD + j) * 128 + 64 + c4);
    }
    float4 wb0 = *(const float4*)(vv + 128 + c4);
    float4 wb1 = *(const float4*)(vv + 128 + 64 + c4);

    // qa = hv_k[n] . w2a
    float qa;
    {
        float4 wa0 = *(const float4*)(vv + c4);
        float4 wa1 = *(const float4*)(vv + 64 + c4);
        const float* hr = HP + (size_t)n * 768 + k * 128;
        float4 h0 = *(const float4*)(hr + c4);
        float4 h1 = *(const float4*)(hr + 64 + c4);
        qa = h0.x * wa0.x + h0.y * wa0.y + h0.z * wa0.z + h0.w * wa0.w
           + h1.x * wa1.x + h1.y * wa1.y + h1.z * wa1.z + h1.w * wa1.w;
#pragma unroll
        for (int d = 1; d < 16; d <<= 1) qa += __shfl_xor(qa, d, 64);
    }

    const int o0 = offp[n];
    const int deg = offp[n + 1] - o0;
    const float* Pn = HP + 384 + (size_t)k * 128;
    float4 a0 = make_float4(0.f, 0.f, 0.f, 0.f);
    float4 a1 = make_float4(0.f, 0.f, 0.f, 0.f);
    float s = 0.f;

    for (int b = 0; b < deg; b += 8) {
        int pA = b + er, pB = b + 4 + er;
        bool onA = pA < deg, onB = pB < deg;
        int qA = o0 + (onA ? pA : 0), qB = o0 + (onB ? pB : 0);
        int snA = csr_src[qA];
        int snB = csr_src[qB];
        const float4* eAp = (const float4*)(EFC + (size_t)qA * 12);
        const float4* eBp = (const float4*)(EFC + (size_t)qB * 12);
        float4 eA0 = eAp[0], eA1 = eAp[1], eA2 = eAp[2];
        float4 eB0 = eBp[0], eB1 = eBp[1], eB2 = eBp[2];
        const float* prA = Pn + (size_t)snA * 768;
        const float* prB = Pn + (size_t)snB * 768;
        float4 xA0 = *(const float4*)(prA + c4);
        float4 xA1 = *(const float4*)(prA + 64 + c4);
        float4 xB0 = *(const float4*)(prB + c4);
        float4 xB1 = *(const float4*)(prB + 64 + c4);
        float efA[12] = {eA0.x, eA0.y, eA0.z, eA0.w, eA1.x, eA1.y, eA1.z, eA1.w,
                         eA2.x, eA2.y, eA2.z, eA2.w};
        float efB[12] = {eB0.x, eB0.y, eB0.z, eB0.w, eB1.x, eB1.y, eB1.z, eB1.w,
                         eB2.x, eB2.y, eB2.z, eB2.w};
#pragma unroll
        for (int j = 0; j < 12; j++) {
            float ea = efA[j], eb = efB[j];
            float4 w0 = Wr[j][0], w1 = Wr[j][1];
            xA0.x += ea * w0.x; xA0.y += ea * w0.y; xA0.z += ea * w0.z; xA0.w += ea * w0.w;
            xA1.x += ea * w1.x; xA1.y += ea * w1.y; xA1.z += ea * w1.z; xA1.w += ea * w1.w;
            xB0.x += eb * w0.x; xB0.y += eb * w0.y; xB0.z += eb * w0.z; xB0.w += eb * w0.w;
            xB1.x += eb * w1.x; xB1.y += eb * w1.y; xB1.z += eb * w1.z; xB1.w += eb * w1.w;
        }
        xA0.x = leakyf(xA0.x); xA0.y = leakyf(xA0.y); xA0.z = leakyf(xA0.z); xA0.w = leakyf(xA0.w);
        xA1.x = leakyf(xA1.x); xA1.y = leakyf(xA1.y); xA1.z = leakyf(xA1.z); xA1.w = leakyf(xA1.w);
        xB0.x = leakyf(xB0.x); xB0.y = leakyf(xB0.y); xB0.z = leakyf(xB0.z); xB0.w = leakyf(xB0.w);
        xB1.x = leakyf(xB1.x); xB1.y = leakyf(xB1.y); xB1.z = leakyf(xB1.z); xB1.w = leakyf(xB1.w);
        float dA = xA0.x * wb0.x + xA0.y * wb0.y + xA0.z * wb0.z + xA0.w * wb0.w
                 + xA1.x * wb1.x + xA1.y * wb1.y + xA1.z * wb1.z + xA1.w * wb1.w;
        float dB = xB0.x * wb0.x + xB0.y * wb0.y + xB0.z * wb0.z + xB0.w * wb0.w
                 + xB1.x * wb1.x + xB1.y * wb1.y + xB1.z * wb1.z + xB1.w * wb1.w;
#pragma unroll
        for (int d = 1; d < 16; d <<= 1) {
            dA += __shfl_xor(dA, d, 64);
            dB += __shfl_xor(dB, d, 64);
        }
        float exA = onA ? __expf(leakyf(qa + dA + b2)) : 0.f;
        float exB = onB ? __expf(leakyf(qa + dB + b2)) : 0.f;
        a0.x += exA * xA0.x + exB * xB0.x; a0.y += exA * xA0.y + exB * xB0.y;
        a0.z += exA * xA0.z + exB * xB0.z; a0.w += exA * xA0.w + exB * xB0.w;
        a1.x += exA * xA1.x + exB * xB1.x; a1.y += exA * xA1.y + exB * xB1.y;
        a1.z += exA * xA1.z + exB * xB1.z; a1.w += exA * xA1.w + exB * xB1.w;
        s += exA + exB;
    }
#pragma unroll
    for (int d = 16; d < 64; d <<= 1) {
        a0.x += __shfl_xor(a0.x, d, 64); a0.y += __shfl_xor(a0.y, d, 64);
        a0.z += __shfl_xor(a0.z, d, 64); a0.w += __shfl_xor(a0.w, d, 64);
        a1.x += __shfl_xor(a1.x, d, 64); a1.y += __shfl_xor(a1.y, d, 64);
        a1.z += __shfl_xor(a1.z, d, 64); a1.w += __shfl_xor(a1.w, d, 64);
        s += __shfl_xor(s, d, 64);
    }
    if (er == 0) {
        float inv = (deg > 0) ? 1.f / s : 0.f;
        a0.x *= inv; a0.y *= inv; a0.z *= inv; a0.w *= inv;
        a1.x *= inv; a1.y *= inv; a1.z *= inv; a1.w *= inv;
        float* arow = AX + (size_t)n * 384 + k * 128;
        *(float4*)(arow + c4) = a0;
        *(float4*)(arow + 64 + c4) = a1;
    }
}

// ================= fused GRU gates + relu =================
__global__ void k_gru2(const float* __restrict__ G, const float* __restrict__ X,
                       const float* __restrict__ bih, const float* __restrict__ bhh,
                       float* __restrict__ out)
{
    int idx = blockIdx.x * 256 + threadIdx.x;
    if (idx >= NN * 128) return;
    int n = idx >> 7, c = idx & 127;
    const float* g = G + (size_t)n * 512;
    float r = 1.f / (1.f + __expf(-(g[c] + bih[c] + bhh[c])));
    float z = 1.f / (1.f + __expf(-(g[128 + c] + bih[128 + c] + bhh[128 + c])));
    float nv = tanhf(g[256 + c] + bih[256 + c] + r * (g[384 + c] + bhh[256 + c]));
    float h = X[(size_t)n * 256 + 128 + c];
    float v = (1.f - z) * nv + z * h;
    out[idx] = v > 0.f ? v : 0.f;
}

extern "C" void kernel_launch(void* const* d_in, const int* in_sizes, int n_in,
                              void* d_out, int out_size, void* d_ws, size_t ws_size,
                              hipStream_t stream)
{
    const float* nf = (const float*)d_in[0];
    const float* ef = (const float*)d_in[1];
    const float *pn_w[3], *pn_b[3], *pe1_w[3], *pe1_b[3], *pe2_w[3], *pe2_b[3], *et_w[3], *et_b[3];
    for (int k = 0; k < 3; k++) {
        int b = 2 + k * 8;
        pn_w[k] = (const float*)d_in[b + 0]; pn_b[k] = (const float*)d_in[b + 1];
        pe1_w[k] = (const float*)d_in[b + 2]; pe1_b[k] = (const float*)d_in[b + 3];
        pe2_w[k] = (const float*)d_in[b + 4]; pe2_b[k] = (const float*)d_in[b + 5];
        et_w[k] = (const float*)d_in[b + 6]; et_b[k] = (const float*)d_in[b + 7];
    }
    const float* mca_w = (const float*)d_in[26]; const float* mca_b = (const float*)d_in[27];
    const float* mcn_w = (const float*)d_in[28]; const float* mcn_b = (const float*)d_in[29];
    const float* wih = (const float*)d_in[30]; const float* whh = (const float*)d_in[31];
    const float* bih = (const float*)d_in[32]; const float* bhh = (const float*)d_in[33];
    const int* src = (const int*)d_in[34];
    const int* dst = (const int*)d_in[35];

    float* W = (float*)d_ws;
    size_t o = 0;
    float* HP = W + o;   o += (size_t)NN * 768;   // hv | Pn->CTX; reused as G [N,512]
    float* AX = W + o;   o += (size_t)NN * 384;   // weighted sums; reused as X [N,256]
    float* EFC = W + o;  o += (size_t)EE * 12;    // CSR-ordered edge feats
    float* PK = W + o;   o += 74 * 768;
    float* PB = W + o;   o += 768;
    float* WG = W + o;   o += 256 * 512;
    float* Z512 = W + o; o += 512;
    int* cnt = (int*)(W + o);
    int* offp = cnt + NN;
    int* cur = offp + NN + 1;
    int* csr_src = cur + NN;
    size_t need = o * 4 + (size_t)(NN * 3 + 1 + EE) * 4;
    if (ws_size < need) return;  // fail loudly (out stays poisoned)

    float* Xb = AX;   // [N,256]
    float* Gb = HP;   // [N,512]

    hipMemsetAsync(cnt, 0, NN * sizeof(int), stream);

    dim3 blk(256);
    k_pack<<<740, blk, 0, stream>>>(
        pn_w[0], pn_w[1], pn_w[2], pn_b[0], pn_b[1], pn_b[2],
        pe1_w[0], pe1_w[1], pe1_w[2], pe1_b[0], pe1_b[1], pe1_b[2],
        wih, whh, PK, PB, WG, Z512);

    const int rt = (NN + 127) / 128;   // 157

    // HP = [leaky(nf@pnw+b) | nf@pe1w+b]
    {
        GJob j = {nf, PK, PB, HP, nullptr, 0, 0};
        gemm256<3><<<dim3(rt * 6, 1), blk, 0, stream>>>(j, j, j, NFD, 768, 768, NN, NFD, 768, 384);
    }

    k_count<<<(EE + 255) / 256, blk, 0, stream>>>(dst, cnt);
    k_scan<<<1, 1024, 0, stream>>>(cnt, offp, cur, NN);
    k_fill<<<(EE + 255) / 256, blk, 0, stream>>>(dst, src, ef, cur, csr_src, EFC);

    // fused: qa + he1k + logits + softmax + weighted aggregation
    k_fused<<<(NN * 3) / 4, blk, 0, stream>>>(HP, EFC,
        pe1_w[0], pe1_w[1], pe1_w[2], pe2_w[0], pe2_w[1], pe2_w[2],
        pe2_b[0], pe2_b[1], pe2_b[2], csr_src, offp, AX);

    // ctx_k = elu(AX_k @ et_w + b) -> HP cols 384.. (batched over k, empty-node guard)
    {
        GJob j0 = {AX, et_w[0], et_b[0], HP, offp, 0 * 128, 384 + 0 * 128};
        GJob j1 = {AX, et_w[1], et_b[1], HP, offp, 1 * 128, 384 + 1 * 128};
        GJob j2 = {AX, et_w[2], et_b[2], HP, offp, 2 * 128, 384 + 2 * 128};
        gemm256<2><<<dim3(rt, 3), blk, 0, stream>>>(j0, j1, j2, 384, 128, 768, NN, 128, 128, 0);
    }
    // X[:,0:128] = ctx@mca_w+b ; X[:,128:256] = hv@mcn_w+b (batched)
    {
        GJob j0 = {HP, mca_w, mca_b, Xb, nullptr, 384, 0};
        GJob j1 = {HP, mcn_w, mcn_b, Xb, nullptr, 0, 128};
        gemm256<0><<<dim3(rt, 2), blk, 0, stream>>>(j0, j1, j1, 768, 128, 256, NN, 384, 128, 0);
    }
    // G = X @ WG  (r|z|in|hn)
    {
        GJob j = {Xb, WG, Z512, Gb, nullptr, 0, 0};
        gemm256<0><<<dim3(rt * 4, 1), blk, 0, stream>>>(j, j, j, 256, 512, 512, NN, 256, 512, 0);
    }

    k_gru2<<<(NN * 128 + 255) / 256, blk, 0, stream>>>(Gb, Xb, bih, bhh, (float*)d_out);
}